// Round 4
// baseline (157.605 us; speedup 1.0000x reference)
//
#include <hip/hip_runtime.h>

// MultiKeyframeProcessor — linear keyframe interpolation.
// latents:       [K=5, B=1, C=128, H=32, W=32] f32
// strengths:     [K=5] f32
// frame_indices: [K=5] i32 (sorted, unique, < 257)
// out: conditioning_latents [1,128,257,32,32] f32 (33,685,504 el)
//      ++ conditioning_masks [1,257] f32 (257 el)
//
// Block decomposition: one block per (c,t) tile of HW=1024 floats (256 float4).
// All keyframe math is block-uniform (scalar unit). Output stores are
// NONTEMPORAL so the 134.7 MB write stream does not evict the 2.6 MB latent
// working set from L2 (round-1 showed ~3x roofline from exactly that).

#define T_FRAMES 257
#define KK 5
#define PER_KEY 131072      // B*C*H*W = 1*128*32*32
#define HW 1024             // 32*32
#define HW4 256             // HW/4
#define LAT_OUT 33685504    // 128*257*1024

typedef float f32x4 __attribute__((ext_vector_type(4)));

__global__ __launch_bounds__(256) void mkp_kernel(
    const float* __restrict__ lat,
    const float* __restrict__ str,
    const int* __restrict__ fi,
    float* __restrict__ out)
{
    const int bx  = blockIdx.x;        // [0, 128*257)
    const int tid = threadIdx.x;       // [0, 256)
    const int c   = bx / T_FRAMES;     // scalar magic-mul
    const int t   = bx - c * T_FRAMES;

    // Keyframe tables: uniform scalar loads, K=5.
    int   fiv[KK];
    float sv[KK];
#pragma unroll
    for (int k = 0; k < KK; ++k) { fiv[k] = fi[k]; sv[k] = str[k]; }

    // searchsorted(fi, t, right) - 1  (block-uniform)
    int j = -1;
#pragma unroll
    for (int k = 0; k < KK; ++k) j += (fiv[k] <= t) ? 1 : 0;
    const int j0 = max(j, 0);
    const int j1 = min(j + 1, KK - 1);

    const bool before   = t < fiv[0];
    const bool after    = t > fiv[KK - 1];
    const bool at_kf    = (fiv[j0] == t);
    const bool interior = !(before || after || at_kf);

    const float tf    = (float)t;
    const float fj0   = (float)fiv[j0];
    const float fj1   = (float)fiv[j1];
    const float denom = fmaxf(fj1 - fj0, 1.0f);
    const float alpha = (tf - fj0) / denom;
    const float w1    = interior ? alpha : 0.0f;
    const float w0    = 1.0f - w1;

    // Latent reads: 2 x float4/lane, contiguous per wave, L2/L1-hot (2.6 MB set).
    const f32x4 a = *((const f32x4*)(lat + j0 * PER_KEY + c * HW) + tid);
    const f32x4 b = *((const f32x4*)(lat + j1 * PER_KEY + c * HW) + tid);
    f32x4 r;
    r.x = w0 * a.x + w1 * b.x;
    r.y = w0 * a.y + w1 * b.y;
    r.z = w0 * a.z + w1 * b.z;
    r.w = w0 * a.w + w1 * b.w;

    // Streaming write: bypass L2 allocation (nt) to keep latents resident.
    __builtin_nontemporal_store(r, ((f32x4*)out) + bx * HW4 + tid);

    // conditioning_masks: blocks with c==0 (bx < 257) cover t = bx.
    if (bx < T_FRAMES && tid == 0) {
        float m;
        if (before) {
            const float f0f = (float)fiv[0];
            m = sv[0] * fmaxf(1.0f - (f0f - tf) / fmaxf(f0f, 1.0f), 0.0f);
        } else if (after) {
            const float fLf = (float)fiv[KK - 1];
            m = sv[KK - 1] * fmaxf(1.0f - (tf - fLf) / ((float)T_FRAMES - fLf), 0.0f);
        } else {
            m = w0 * sv[j0] + w1 * sv[j1];
        }
        out[LAT_OUT + t] = m;
    }
}

extern "C" void kernel_launch(void* const* d_in, const int* in_sizes, int n_in,
                              void* d_out, int out_size, void* d_ws, size_t ws_size,
                              hipStream_t stream)
{
    const float* lat = (const float*)d_in[0];
    const float* str = (const float*)d_in[1];
    const int*   fi  = (const int*)d_in[2];
    float* out = (float*)d_out;

    const int grid = 128 * T_FRAMES;   // one block per (c,t) tile
    mkp_kernel<<<grid, 256, 0, stream>>>(lat, str, fi, out);
}

// Round 5
// 154.060 us; speedup vs baseline: 1.0230x; 1.0230x over previous
//
#include <hip/hip_runtime.h>

// MultiKeyframeProcessor — linear keyframe interpolation.
// latents:       [K=5, B=1, C=128, H=32, W=32] f32   (2.6 MB total)
// strengths:     [K=5] f32
// frame_indices: [K=5] i32 (sorted, unique, < 257)
// out: conditioning_latents [1,128,257,32,32] f32 (33,685,504 el, 134.7 MB)
//      ++ conditioning_masks [1,257] f32 (257 el)
//
// Round-5 structure: grid = 257*8 blocks. Block b handles t = b>>3 and
// channel chunk e = b&7 (16 channels = 64 KB of output). Rationale:
//  - round-robin XCD assignment puts chunk e on XCD e -> per-XCD read set
//    is only ~320 KB (5 kf x 16 ch x 4 KB), L2-resident under write pressure.
//  - 16 independent loop iterations/thread give ILP to hide read latency
//    (round-4's single load-fma-store chain per thread had none).
//  - all keyframe math is block-uniform (scalar unit).
// NT stores keep the 134.7 MB write stream from allocating in L2.

#define T_FRAMES 257
#define KK 5
#define PER_KEY 131072      // B*C*H*W = 1*128*32*32
#define HW 1024             // 32*32
#define LAT_OUT 33685504    // 128*257*1024
#define CCHUNK 16           // channels per block (128/8)

typedef float f32x4 __attribute__((ext_vector_type(4)));

__global__ __launch_bounds__(256) void mkp_kernel(
    const float* __restrict__ lat,
    const float* __restrict__ str,
    const int* __restrict__ fi,
    float* __restrict__ out)
{
    const int b   = blockIdx.x;        // [0, 257*8)
    const int tid = threadIdx.x;       // [0, 256)
    const int t   = b >> 3;
    const int e   = b & 7;

    // Keyframe tables: uniform scalar loads, K=5.
    int   fiv[KK];
    float sv[KK];
#pragma unroll
    for (int k = 0; k < KK; ++k) { fiv[k] = fi[k]; sv[k] = str[k]; }

    // searchsorted(fi, t, right) - 1  (block-uniform)
    int j = -1;
#pragma unroll
    for (int k = 0; k < KK; ++k) j += (fiv[k] <= t) ? 1 : 0;
    const int j0 = max(j, 0);
    const int j1 = min(j + 1, KK - 1);

    const bool before   = t < fiv[0];
    const bool after    = t > fiv[KK - 1];
    const bool at_kf    = (fiv[j0] == t);
    const bool interior = !(before || after || at_kf);

    const float tf    = (float)t;
    const float fj0   = (float)fiv[j0];
    const float fj1   = (float)fiv[j1];
    const float denom = fmaxf(fj1 - fj0, 1.0f);
    const float alpha = (tf - fj0) / denom;
    const float w1    = interior ? alpha : 0.0f;
    const float w0    = 1.0f - w1;

    // Base pointers (block-uniform scalar offsets).
    const float* p0 = lat + j0 * PER_KEY + (e * CCHUNK) * HW;
    const float* p1 = lat + j1 * PER_KEY + (e * CCHUNK) * HW;
    float*       po = out + ((e * CCHUNK) * T_FRAMES + t) * HW;

    // 16 channels, 4-way independent slots for ILP.
#pragma unroll 4
    for (int i = 0; i < CCHUNK; ++i) {
        const f32x4 a = *((const f32x4*)(p0 + i * HW) + tid);
        const f32x4 v = *((const f32x4*)(p1 + i * HW) + tid);
        f32x4 r;
        r.x = w0 * a.x + w1 * v.x;
        r.y = w0 * a.y + w1 * v.y;
        r.z = w0 * a.z + w1 * v.z;
        r.w = w0 * a.w + w1 * v.w;
        __builtin_nontemporal_store(r, (f32x4*)(po + i * (T_FRAMES * HW)) + tid);
    }

    // conditioning_masks: one scalar store per t (chunk-0 blocks only).
    if (e == 0 && tid == 0) {
        float m;
        if (before) {
            const float f0f = (float)fiv[0];
            m = sv[0] * fmaxf(1.0f - (f0f - tf) / fmaxf(f0f, 1.0f), 0.0f);
        } else if (after) {
            const float fLf = (float)fiv[KK - 1];
            m = sv[KK - 1] * fmaxf(1.0f - (tf - fLf) / ((float)T_FRAMES - fLf), 0.0f);
        } else {
            m = w0 * sv[j0] + w1 * sv[j1];
        }
        out[LAT_OUT + t] = m;
    }
}

extern "C" void kernel_launch(void* const* d_in, const int* in_sizes, int n_in,
                              void* d_out, int out_size, void* d_ws, size_t ws_size,
                              hipStream_t stream)
{
    const float* lat = (const float*)d_in[0];
    const float* str = (const float*)d_in[1];
    const int*   fi  = (const int*)d_in[2];
    float* out = (float*)d_out;

    const int grid = T_FRAMES * 8;   // 2056 blocks: (t, channel-chunk)
    mkp_kernel<<<grid, 256, 0, stream>>>(lat, str, fi, out);
}

// Round 6
// 149.543 us; speedup vs baseline: 1.0539x; 1.0302x over previous
//
#include <hip/hip_runtime.h>

// MultiKeyframeProcessor — linear keyframe interpolation.
// latents:       [K=5, B=1, C=128, H=32, W=32] f32   (2.6 MB total)
// strengths:     [K=5] f32
// frame_indices: [K=5] i32 (sorted, unique, < 257)
// out: conditioning_latents [1,128,257,32,32] f32 (134.7 MB)
//      ++ conditioning_masks [1,257] f32
//
// Round-6 structure: REGISTER-RESIDENT keyframes. Grid = 8 t-groups x 128
// channels. Each thread owns one float4 of its channel's HW plane, loads the
// 5 keyframe values for it ONCE (5 x f32x4 = 20 VGPR), then loops over its
// 33-frame t-range doing pure register FMA + nontemporal streaming stores.
// No reads in the inner loop at all -> HBM traffic = 2.6 MB read + 134.7 MB
// write = write roofline (~22 us).
//  - per-t weights are a 5-vector of block-uniform scalars with compile-time
//    indexing (no runtime-indexed register array -> no scratch).
//  - block b: c = b&127 -> XCD c%8; writes are one contiguous region per
//    block (fixed c, consecutive t).

#define T_FRAMES 257
#define KK 5
#define PER_KEY 131072      // 1*128*32*32
#define HW 1024             // 32*32
#define LAT_OUT 33685504    // 128*257*1024
#define TGROUPS 8
#define TLEN 33             // ceil(257/8)

typedef float f32x4 __attribute__((ext_vector_type(4)));

__global__ __launch_bounds__(256) void mkp_kernel(
    const float* __restrict__ lat,
    const float* __restrict__ str,
    const int* __restrict__ fi,
    float* __restrict__ out)
{
    const int b   = blockIdx.x;        // [0, 8*128)
    const int tid = threadIdx.x;       // [0, 256)
    const int g   = b >> 7;            // t-group
    const int c   = b & 127;           // channel

    // Keyframe tables: uniform scalar loads, K=5.
    int   fiv[KK];
    float sv[KK];
#pragma unroll
    for (int k = 0; k < KK; ++k) { fiv[k] = fi[k]; sv[k] = str[k]; }

    // Load this thread's 5 keyframe float4s into registers (read-once).
    f32x4 kf[KK];
#pragma unroll
    for (int k = 0; k < KK; ++k)
        kf[k] = *((const f32x4*)(lat + k * PER_KEY + c * HW) + tid);

    const int t0 = g * TLEN;
    const int t1 = (t0 + TLEN < T_FRAMES) ? t0 + TLEN : T_FRAMES;

    float* po = out + c * (T_FRAMES * HW);   // channel base

    for (int t = t0; t < t1; ++t) {
        // searchsorted + weights (block-uniform math, cheap).
        int j = -1;
#pragma unroll
        for (int k = 0; k < KK; ++k) j += (fiv[k] <= t) ? 1 : 0;
        const int j0 = (j < 0) ? 0 : j;
        const int j1 = (j + 1 > KK - 1) ? KK - 1 : j + 1;

        const bool before   = t < fiv[0];
        const bool after    = t > fiv[KK - 1];
        const bool at_kf    = (fiv[j0] == t);
        const bool interior = !(before || after || at_kf);

        const float tf    = (float)t;
        const float fj0   = (float)fiv[j0];
        const float fj1   = (float)fiv[j1];
        const float denom = fmaxf(fj1 - fj0, 1.0f);
        const float alpha = (tf - fj0) / denom;
        const float w1    = interior ? alpha : 0.0f;
        const float w0    = 1.0f - w1;

        // 5-wide weight vector, compile-time indexed (no scratch).
        float wk[KK];
#pragma unroll
        for (int k = 0; k < KK; ++k)
            wk[k] = ((k == j0) ? w0 : 0.0f) + ((k == j1) ? w1 : 0.0f);

        f32x4 r = kf[0] * wk[0];
#pragma unroll
        for (int k = 1; k < KK; ++k) {
            r.x = fmaf(kf[k].x, wk[k], r.x);
            r.y = fmaf(kf[k].y, wk[k], r.y);
            r.z = fmaf(kf[k].z, wk[k], r.z);
            r.w = fmaf(kf[k].w, wk[k], r.w);
        }

        __builtin_nontemporal_store(r, (f32x4*)(po + t * HW) + tid);
    }

    // conditioning_masks: c==0 blocks, one thread per t in the group's range.
    if (c == 0 && tid < (t1 - t0)) {
        const int t = t0 + tid;
        int j = -1;
#pragma unroll
        for (int k = 0; k < KK; ++k) j += (fiv[k] <= t) ? 1 : 0;
        const int j0 = (j < 0) ? 0 : j;
        const int j1 = (j + 1 > KK - 1) ? KK - 1 : j + 1;

        const bool before   = t < fiv[0];
        const bool after    = t > fiv[KK - 1];
        const bool at_kf    = (fiv[j0] == t);
        const bool interior = !(before || after || at_kf);

        const float tf    = (float)t;
        const float fj0   = (float)fiv[j0];
        const float fj1   = (float)fiv[j1];
        const float denom = fmaxf(fj1 - fj0, 1.0f);
        const float alpha = (tf - fj0) / denom;
        const float w1    = interior ? alpha : 0.0f;
        const float w0    = 1.0f - w1;

        float m;
        if (before) {
            const float f0f = (float)fiv[0];
            m = sv[0] * fmaxf(1.0f - (f0f - tf) / fmaxf(f0f, 1.0f), 0.0f);
        } else if (after) {
            const float fLf = (float)fiv[KK - 1];
            m = sv[KK - 1] * fmaxf(1.0f - (tf - fLf) / ((float)T_FRAMES - fLf), 0.0f);
        } else {
            m = w0 * sv[j0] + w1 * sv[j1];
        }
        out[LAT_OUT + t] = m;
    }
}

extern "C" void kernel_launch(void* const* d_in, const int* in_sizes, int n_in,
                              void* d_out, int out_size, void* d_ws, size_t ws_size,
                              hipStream_t stream)
{
    const float* lat = (const float*)d_in[0];
    const float* str = (const float*)d_in[1];
    const int*   fi  = (const int*)d_in[2];
    float* out = (float*)d_out;

    const int grid = TGROUPS * 128;   // 1024 blocks: (t-group, channel)
    mkp_kernel<<<grid, 256, 0, stream>>>(lat, str, fi, out);
}

// Round 7
// 144.771 us; speedup vs baseline: 1.0886x; 1.0330x over previous
//
#include <hip/hip_runtime.h>

// MultiKeyframeProcessor — linear keyframe interpolation.
// latents:       [K=5, B=1, C=128, H=32, W=32] f32   (2.6 MB total)
// strengths:     [K=5] f32
// frame_indices: [K=5] i32 (sorted, unique, < 257)
// out: conditioning_latents [1,128,257,32,32] f32 (134.7 MB)
//      ++ conditioning_masks [1,257] f32
//
// Round-7: register-resident keyframes (round-6 structure), but PLAIN stores
// instead of nontemporal. Round-6 post-mortem: with zero inner-loop reads the
// kernel still ran ~60 us (~2.2 TB/s store rate) while the harness fillBuffer
// sustains 6.27 TB/s with plain stores — suspecting the nt flag defeats L2
// write-combining. Reads don't need L2 protection (proven rounds 4-6).
// Grid = 16 t-groups x 128 channels = 2048 blocks; each thread owns one
// float4 of a channel plane, loads 5 keyframe f32x4 once (20 VGPR), then
// 17 iterations of pure register FMA + contiguous 4KB/block-iteration stores.

#define T_FRAMES 257
#define KK 5
#define PER_KEY 131072      // 1*128*32*32
#define HW 1024             // 32*32
#define LAT_OUT 33685504    // 128*257*1024
#define TGROUPS 16
#define TLEN 17             // ceil(257/16)

typedef float f32x4 __attribute__((ext_vector_type(4)));

__global__ __launch_bounds__(256) void mkp_kernel(
    const float* __restrict__ lat,
    const float* __restrict__ str,
    const int* __restrict__ fi,
    float* __restrict__ out)
{
    const int b   = blockIdx.x;        // [0, 16*128)
    const int tid = threadIdx.x;       // [0, 256)
    const int g   = b >> 7;            // t-group
    const int c   = b & 127;           // channel

    // Keyframe tables: uniform scalar loads, K=5.
    int   fiv[KK];
    float sv[KK];
#pragma unroll
    for (int k = 0; k < KK; ++k) { fiv[k] = fi[k]; sv[k] = str[k]; }

    // Load this thread's 5 keyframe float4s into registers (read-once).
    f32x4 kf[KK];
#pragma unroll
    for (int k = 0; k < KK; ++k)
        kf[k] = *((const f32x4*)(lat + k * PER_KEY + c * HW) + tid);

    const int t0 = g * TLEN;
    const int t1 = (t0 + TLEN < T_FRAMES) ? t0 + TLEN : T_FRAMES;

    float* po = out + c * (T_FRAMES * HW);   // channel base

    for (int t = t0; t < t1; ++t) {
        // searchsorted + weights (block-uniform math, cheap).
        int j = -1;
#pragma unroll
        for (int k = 0; k < KK; ++k) j += (fiv[k] <= t) ? 1 : 0;
        const int j0 = (j < 0) ? 0 : j;
        const int j1 = (j + 1 > KK - 1) ? KK - 1 : j + 1;

        const bool before   = t < fiv[0];
        const bool after    = t > fiv[KK - 1];
        const bool at_kf    = (fiv[j0] == t);
        const bool interior = !(before || after || at_kf);

        const float tf    = (float)t;
        const float fj0   = (float)fiv[j0];
        const float fj1   = (float)fiv[j1];
        const float denom = fmaxf(fj1 - fj0, 1.0f);
        const float alpha = (tf - fj0) / denom;
        const float w1    = interior ? alpha : 0.0f;
        const float w0    = 1.0f - w1;

        // 5-wide weight vector, compile-time indexed (no scratch).
        float wk[KK];
#pragma unroll
        for (int k = 0; k < KK; ++k)
            wk[k] = ((k == j0) ? w0 : 0.0f) + ((k == j1) ? w1 : 0.0f);

        f32x4 r = kf[0] * wk[0];
#pragma unroll
        for (int k = 1; k < KK; ++k) {
            r.x = fmaf(kf[k].x, wk[k], r.x);
            r.y = fmaf(kf[k].y, wk[k], r.y);
            r.z = fmaf(kf[k].z, wk[k], r.z);
            r.w = fmaf(kf[k].w, wk[k], r.w);
        }

        *((f32x4*)(po + t * HW) + tid) = r;   // plain store (write-back L2)
    }

    // conditioning_masks: c==0 blocks, one thread per t in the group's range.
    if (c == 0 && tid < (t1 - t0)) {
        const int t = t0 + tid;
        int j = -1;
#pragma unroll
        for (int k = 0; k < KK; ++k) j += (fiv[k] <= t) ? 1 : 0;
        const int j0 = (j < 0) ? 0 : j;
        const int j1 = (j + 1 > KK - 1) ? KK - 1 : j + 1;

        const bool before   = t < fiv[0];
        const bool after    = t > fiv[KK - 1];
        const bool at_kf    = (fiv[j0] == t);
        const bool interior = !(before || after || at_kf);

        const float tf    = (float)t;
        const float fj0   = (float)fiv[j0];
        const float fj1   = (float)fiv[j1];
        const float denom = fmaxf(fj1 - fj0, 1.0f);
        const float alpha = (tf - fj0) / denom;
        const float w1    = interior ? alpha : 0.0f;
        const float w0    = 1.0f - w1;

        float m;
        if (before) {
            const float f0f = (float)fiv[0];
            m = sv[0] * fmaxf(1.0f - (f0f - tf) / fmaxf(f0f, 1.0f), 0.0f);
        } else if (after) {
            const float fLf = (float)fiv[KK - 1];
            m = sv[KK - 1] * fmaxf(1.0f - (tf - fLf) / ((float)T_FRAMES - fLf), 0.0f);
        } else {
            m = w0 * sv[j0] + w1 * sv[j1];
        }
        out[LAT_OUT + t] = m;
    }
}

extern "C" void kernel_launch(void* const* d_in, const int* in_sizes, int n_in,
                              void* d_out, int out_size, void* d_ws, size_t ws_size,
                              hipStream_t stream)
{
    const float* lat = (const float*)d_in[0];
    const float* str = (const float*)d_in[1];
    const int*   fi  = (const int*)d_in[2];
    float* out = (float*)d_out;

    const int grid = TGROUPS * 128;   // 2048 blocks: (t-group, channel)
    mkp_kernel<<<grid, 256, 0, stream>>>(lat, str, fi, out);
}

// Round 8
// 140.718 us; speedup vs baseline: 1.1200x; 1.0288x over previous
//
#include <hip/hip_runtime.h>

// MultiKeyframeProcessor — linear keyframe interpolation.
// latents:       [K=5, B=1, C=128, H=32, W=32] f32   (2.6 MB total)
// strengths:     [K=5] f32
// frame_indices: [K=5] i32 (sorted, unique, < 257)
// out: conditioning_latents [1,128,257,32,32] f32 (134.7 MB)
//      ++ conditioning_masks [1,257] f32
//
// Round-8: CONTIGUOUS PER-WAVE STORE STREAMS (fill-like). Round-7 showed the
// kernel's internals barely matter; the store stream runs at ~2-3 TB/s while
// the harness fillBuffer (plain stores, contiguous grid-stride per wave,
// ~768 waves) hits 6.6 TB/s. Our previous layout had 8192 concurrent
// 4KB-strided wave streams. Here: grid = 256 blocks = (half, c); each block's
// 4 waves own 32-33 consecutive t-planes of channel c and write each 4KB
// plane as 4 back-to-back 1KB wave stores -> 512 sequential ~130KB streams.
// Keyframes are register-resident (5 kf x 4 quarter-plane f32x4 = 80 VGPR).

#define T_FRAMES 257
#define KK 5
#define PER_KEY 131072      // 1*128*32*32
#define HW 1024             // 32*32
#define LAT_OUT 33685504    // 128*257*1024

typedef float f32x4 __attribute__((ext_vector_type(4)));

__global__ __launch_bounds__(256) void mkp_kernel(
    const float* __restrict__ lat,
    const float* __restrict__ str,
    const int* __restrict__ fi,
    float* __restrict__ out)
{
    const int b    = blockIdx.x;        // [0, 256)
    const int tid  = threadIdx.x;       // [0, 256)
    const int c    = b & 127;           // channel
    const int h    = b >> 7;            // t half
    const int w    = tid >> 6;          // wave in block
    const int lane = tid & 63;

    // Keyframe tables: uniform scalar loads, K=5.
    int   fiv[KK];
    float sv[KK];
#pragma unroll
    for (int k = 0; k < KK; ++k) { fiv[k] = fi[k]; sv[k] = str[k]; }

    // Register-resident keyframe plane: lane l holds quarter-plane q's
    // f32x4 at float offset q*256 + l*4, for all 5 keyframes.
    f32x4 kf[KK][4];
#pragma unroll
    for (int k = 0; k < KK; ++k) {
        const f32x4* src = (const f32x4*)(lat + k * PER_KEY + c * HW);
#pragma unroll
        for (int q = 0; q < 4; ++q)
            kf[k][q] = src[q * 64 + lane];
    }

    // This wave's contiguous t-range.
    const int t0 = h * 128 + w * 32;
    const int t1 = (h == 1 && w == 3) ? 257 : t0 + 32;

    const float* dummy; (void)dummy;
    float* po = out + c * (T_FRAMES * HW);   // channel base

    for (int t = t0; t < t1; ++t) {
        // searchsorted + weights (wave-uniform math, cheap).
        int j = -1;
#pragma unroll
        for (int k = 0; k < KK; ++k) j += (fiv[k] <= t) ? 1 : 0;
        const int j0 = (j < 0) ? 0 : j;
        const int j1 = (j + 1 > KK - 1) ? KK - 1 : j + 1;

        const bool before   = t < fiv[0];
        const bool after    = t > fiv[KK - 1];
        const bool at_kf    = (fiv[j0] == t);
        const bool interior = !(before || after || at_kf);

        const float tf    = (float)t;
        const float fj0   = (float)fiv[j0];
        const float fj1   = (float)fiv[j1];
        const float denom = fmaxf(fj1 - fj0, 1.0f);
        const float alpha = (tf - fj0) / denom;
        const float w1    = interior ? alpha : 0.0f;
        const float w0    = 1.0f - w1;

        // 5-wide weight vector, compile-time indexed (no scratch).
        float wk[KK];
#pragma unroll
        for (int k = 0; k < KK; ++k)
            wk[k] = ((k == j0) ? w0 : 0.0f) + ((k == j1) ? w1 : 0.0f);

        f32x4* plane4 = (f32x4*)(po + t * HW);
        // 4 back-to-back 1KB wave-stores: per-wave address stream is fully
        // sequential across the whole t-range (~130KB contiguous).
#pragma unroll
        for (int q = 0; q < 4; ++q) {
            f32x4 r = kf[0][q] * wk[0];
#pragma unroll
            for (int k = 1; k < KK; ++k) {
                r.x = fmaf(kf[k][q].x, wk[k], r.x);
                r.y = fmaf(kf[k][q].y, wk[k], r.y);
                r.z = fmaf(kf[k][q].z, wk[k], r.z);
                r.w = fmaf(kf[k][q].w, wk[k], r.w);
            }
            plane4[q * 64 + lane] = r;
        }
    }

    // conditioning_masks: c==0 blocks; h=0 covers t=0..127, h=1 covers 128..256.
    const int nmask = (h == 0) ? 128 : 129;
    if (c == 0 && tid < nmask) {
        const int t = h * 128 + tid;
        int j = -1;
#pragma unroll
        for (int k = 0; k < KK; ++k) j += (fiv[k] <= t) ? 1 : 0;
        const int j0 = (j < 0) ? 0 : j;
        const int j1 = (j + 1 > KK - 1) ? KK - 1 : j + 1;

        const bool before   = t < fiv[0];
        const bool after    = t > fiv[KK - 1];
        const bool at_kf    = (fiv[j0] == t);
        const bool interior = !(before || after || at_kf);

        const float tf    = (float)t;
        const float fj0   = (float)fiv[j0];
        const float fj1   = (float)fiv[j1];
        const float denom = fmaxf(fj1 - fj0, 1.0f);
        const float alpha = (tf - fj0) / denom;
        const float w1    = interior ? alpha : 0.0f;
        const float w0    = 1.0f - w1;

        float m;
        if (before) {
            const float f0f = (float)fiv[0];
            m = sv[0] * fmaxf(1.0f - (f0f - tf) / fmaxf(f0f, 1.0f), 0.0f);
        } else if (after) {
            const float fLf = (float)fiv[KK - 1];
            m = sv[KK - 1] * fmaxf(1.0f - (tf - fLf) / ((float)T_FRAMES - fLf), 0.0f);
        } else {
            m = w0 * sv[j0] + w1 * sv[j1];
        }
        out[LAT_OUT + t] = m;
    }
}

extern "C" void kernel_launch(void* const* d_in, const int* in_sizes, int n_in,
                              void* d_out, int out_size, void* d_ws, size_t ws_size,
                              hipStream_t stream)
{
    const float* lat = (const float*)d_in[0];
    const float* str = (const float*)d_in[1];
    const int*   fi  = (const int*)d_in[2];
    float* out = (float*)d_out;

    const int grid = 256;   // (t-half, channel): 1 block/CU, 4 waves each
    mkp_kernel<<<grid, 256, 0, stream>>>(lat, str, fi, out);
}